// Round 3
// baseline (57.388 us; speedup 1.0000x reference)
//
#include <hip/hip_runtime.h>

#define BS   2
#define NCTX 2048
#define NH   8
#define WD   32
#define NTOK 512

static constexpr float SCALE = 0.04419417382415922f; // 1/sqrt(512)

// wave = 32 rows x one 32-j chunk; lane = whalf*32 + r
// block = 1024 threads = 16 waves = all 16 j-chunks of one 32-row group
// grid  = 16 (b,h) planes x 16 row-groups = 256 blocks (1 per CU)

struct RowBuf {
  float4 q0, q1, q2, q3;
  float4 v0, v1, v2, v3;
};

__device__ __forceinline__ void issue_rows(const char* __restrict__ qp0,
                                           const char* __restrict__ vp0,
                                           int tok, RowBuf& B) {
  const char* qp = qp0 + ((size_t)tok << 10);   // token row = 256 floats = 1024 B
  const char* vp = vp0 + ((size_t)tok << 10);
  B.q0 = *(const float4*)(qp +  0);
  B.q1 = *(const float4*)(qp + 16);
  B.q2 = *(const float4*)(qp + 32);
  B.q3 = *(const float4*)(qp + 48);
  B.v0 = *(const float4*)(vp +  0);
  B.v1 = *(const float4*)(vp + 16);
  B.v2 = *(const float4*)(vp + 32);
  B.v3 = *(const float4*)(vp + 48);
}

__device__ __forceinline__ void body(const RowBuf& Bf, const float kg[16],
                                     float& l, float acc[16]) {
  float d0, d1, d2, d3;
  d0  = fabsf(kg[ 0] - Bf.q0.x);
  d1  = fabsf(kg[ 1] - Bf.q0.y);
  d2  = fabsf(kg[ 2] - Bf.q0.z);
  d3  = fabsf(kg[ 3] - Bf.q0.w);
  d0 += fabsf(kg[ 4] - Bf.q1.x);
  d1 += fabsf(kg[ 5] - Bf.q1.y);
  d2 += fabsf(kg[ 6] - Bf.q1.z);
  d3 += fabsf(kg[ 7] - Bf.q1.w);
  d0 += fabsf(kg[ 8] - Bf.q2.x);
  d1 += fabsf(kg[ 9] - Bf.q2.y);
  d2 += fabsf(kg[10] - Bf.q2.z);
  d3 += fabsf(kg[11] - Bf.q2.w);
  d0 += fabsf(kg[12] - Bf.q3.x);
  d1 += fabsf(kg[13] - Bf.q3.y);
  d2 += fabsf(kg[14] - Bf.q3.z);
  d3 += fabsf(kg[15] - Bf.q3.w);
  float d = (d0 + d1) + (d2 + d3);
  d += __shfl_xor(d, 32, 64);          // combine the two w-halves of this row
  float p = __expf(-SCALE * d);        // d in [0, ~350]: no max-shift needed
  l += p;
  acc[ 0] = fmaf(p, Bf.v0.x, acc[ 0]);
  acc[ 1] = fmaf(p, Bf.v0.y, acc[ 1]);
  acc[ 2] = fmaf(p, Bf.v0.z, acc[ 2]);
  acc[ 3] = fmaf(p, Bf.v0.w, acc[ 3]);
  acc[ 4] = fmaf(p, Bf.v1.x, acc[ 4]);
  acc[ 5] = fmaf(p, Bf.v1.y, acc[ 5]);
  acc[ 6] = fmaf(p, Bf.v1.z, acc[ 6]);
  acc[ 7] = fmaf(p, Bf.v1.w, acc[ 7]);
  acc[ 8] = fmaf(p, Bf.v2.x, acc[ 8]);
  acc[ 9] = fmaf(p, Bf.v2.y, acc[ 9]);
  acc[10] = fmaf(p, Bf.v2.z, acc[10]);
  acc[11] = fmaf(p, Bf.v2.w, acc[11]);
  acc[12] = fmaf(p, Bf.v3.x, acc[12]);
  acc[13] = fmaf(p, Bf.v3.y, acc[13]);
  acc[14] = fmaf(p, Bf.v3.z, acc[14]);
  acc[15] = fmaf(p, Bf.v3.w, acc[15]);
}

__global__ void __launch_bounds__(1024, 4)
l1attn_v3(const float* __restrict__ q, const float* __restrict__ k,
          const float* __restrict__ v, const int* __restrict__ indx,
          float* __restrict__ out) {
  __shared__ int   indxS[NTOK];
  __shared__ float accS[32 * 33];     // [row][w], stride 33
  __shared__ float lS[32];

  const int tid = threadIdx.x;

  if (tid < NTOK) indxS[tid] = indx[tid];
  for (int i = tid; i < 32 * 33; i += 1024) accS[i] = 0.f;
  if (tid < 32) lS[tid] = 0.f;
  __syncthreads();

  const int wave  = __builtin_amdgcn_readfirstlane(tid >> 6); // 0..15 = j-chunk
  const int lane  = tid & 63;
  const int whalf = lane >> 5;        // which 16 of the 32 w's
  const int r     = lane & 31;        // row within group

  const int bh = blockIdx.x >> 4;
  const int g  = blockIdx.x & 15;
  const int b  = bh >> 3;
  const int h  = bh & 7;
  const int s  = g * 32 + r;          // gathered row index [0,512)

  const char* qb = (const char*)(q + ((size_t)b * NCTX * NH + h) * WD + whalf * 16);
  const char* vb = (const char*)(v + ((size_t)b * NCTX * NH + h) * WD + whalf * 16);
  const float* kb =              k + ((size_t)b * NCTX * NH + h) * WD + whalf * 16;

  // this lane's half of the K row for row s (rows key on k per the einsum)
  float kg[16];
  {
    const float4* kr = (const float4*)(kb + (size_t)indxS[s] * (NH * WD));
#pragma unroll
    for (int i = 0; i < 4; ++i) {
      float4 t = kr[i];
      kg[4*i+0] = t.x; kg[4*i+1] = t.y; kg[4*i+2] = t.z; kg[4*i+3] = t.w;
    }
  }

  float acc[16];
#pragma unroll
  for (int i = 0; i < 16; ++i) acc[i] = 0.f;
  float l = 0.f;

  const int jb = wave * 32;

  RowBuf A, B;
  issue_rows(qb, vb, indxS[jb + 0], A);
  issue_rows(qb, vb, indxS[jb + 1], B);
  __builtin_amdgcn_sched_barrier(0);

  for (int jj = 0; jj < 32; jj += 2) {
    const int tok2 = indxS[jb + ((jj + 2) & 31)]; // wrap: final prefetch unused
    const int tok3 = indxS[jb + ((jj + 3) & 31)];

    body(A, kg, l, acc);
    issue_rows(qb, vb, tok2, A);
    __builtin_amdgcn_sched_barrier(0);

    body(B, kg, l, acc);
    issue_rows(qb, vb, tok3, B);
    __builtin_amdgcn_sched_barrier(0);
  }

  // combine the 16 j-chunk partials in LDS
#pragma unroll
  for (int i = 0; i < 16; ++i)
    atomicAdd(&accS[r * 33 + whalf * 16 + i], acc[i]);
  if (whalf == 0) atomicAdd(&lS[r], l);
  __syncthreads();

  // write out: thread -> (row rr, w ww), coalesced
  {
    const int rr = tid >> 5;
    const int ww = tid & 31;
    const float res = accS[rr * 33 + ww] / lS[rr];
    const int ss = g * 32 + rr;
    out[(((size_t)b * NTOK + ss) * NH + h) * WD + ww] = res;
  }
}

extern "C" void kernel_launch(void* const* d_in, const int* in_sizes, int n_in,
                              void* d_out, int out_size, void* d_ws, size_t ws_size,
                              hipStream_t stream) {
  const float* q    = (const float*)d_in[0];
  const float* k    = (const float*)d_in[1];
  const float* v    = (const float*)d_in[2];
  const int*   indx = (const int*)d_in[3];
  float*       out  = (float*)d_out;

  dim3 grid(256), block(1024);
  hipLaunchKernelGGL(l1attn_v3, grid, block, 0, stream, q, k, v, indx, out);
}